// Round 1
// baseline (409.155 us; speedup 1.0000x reference)
//
#include <hip/hip_runtime.h>
#include <math.h>

#define M_SLOTS 60
#define B_SZ    64
#define C_CH    256
#define HW      3136          // 56*56
#define POS     (C_CH * HW)   // 802816 positions per memory slot / per batch
#define EPS     1e-8f

// ---------------------------------------------------------------------------
// Kernel A: per-(m,c) row sum of 3136 spatial elements. One wave per row.
// grid = 15360/4 blocks, block = 256 (4 waves, 1 row each).
// ---------------------------------------------------------------------------
__global__ __launch_bounds__(256) void avg_kernel(const float* __restrict__ pool,
                                                  float* __restrict__ sums) {
    const int row  = blockIdx.x * 4 + (threadIdx.x >> 6);  // [0, 15360)
    const int lane = threadIdx.x & 63;
    const float4* r4 = (const float4*)(pool + (size_t)row * HW);  // HW*4B is 16B-aligned (12544)
    float s = 0.0f;
    for (int i = lane; i < HW / 4; i += 64) {   // 784 float4 per row
        float4 v = r4[i];
        s += v.x + v.y + v.z + v.w;
    }
    #pragma unroll
    for (int off = 32; off; off >>= 1) s += __shfl_down(s, off);
    if (lane == 0) sums[row] = s;
}

// ---------------------------------------------------------------------------
// Kernel B: cosine sim + softmax. grid = 64 (one block per b), block = 256.
// Writes transposed weights wT[m*64 + b].
// ---------------------------------------------------------------------------
__global__ __launch_bounds__(256) void weights_kernel(const float* __restrict__ q,
                                                      const float* __restrict__ sums,
                                                      float* __restrict__ wT) {
    const int b    = blockIdx.x;
    const int wave = threadIdx.x >> 6;
    const int lane = threadIdx.x & 63;
    const float inv = 1.0f / (float)HW;

    __shared__ float s_cos[M_SLOTS];

    // each lane holds 4 channels of q[b]; each wave computes qn redundantly (no sync needed)
    float4 qv = ((const float4*)(q + b * C_CH))[lane];
    float qn2 = qv.x*qv.x + qv.y*qv.y + qv.z*qv.z + qv.w*qv.w;
    #pragma unroll
    for (int off = 32; off; off >>= 1) qn2 += __shfl_down(qn2, off);
    qn2 = __shfl(qn2, 0);
    const float qn = fmaxf(sqrtf(qn2), EPS);

    // waves split the 60 memory slots
    for (int m = wave; m < M_SLOTS; m += 4) {
        float4 mv = ((const float4*)(sums + m * C_CH))[lane];
        mv.x *= inv; mv.y *= inv; mv.z *= inv; mv.w *= inv;
        float dot = qv.x*mv.x + qv.y*mv.y + qv.z*mv.z + qv.w*mv.w;
        float mn2 = mv.x*mv.x + mv.y*mv.y + mv.z*mv.z + mv.w*mv.w;
        #pragma unroll
        for (int off = 32; off; off >>= 1) {
            dot += __shfl_down(dot, off);
            mn2 += __shfl_down(mn2, off);
        }
        if (lane == 0) {
            float mn = fmaxf(sqrtf(mn2), EPS);
            s_cos[m] = dot / (qn * mn);
        }
    }
    __syncthreads();

    if (wave == 0) {
        float c = (lane < M_SLOTS) ? s_cos[lane] : -INFINITY;
        float mx = c;
        #pragma unroll
        for (int off = 32; off; off >>= 1) mx = fmaxf(mx, __shfl_down(mx, off));
        mx = __shfl(mx, 0);
        float e = (lane < M_SLOTS) ? __expf(c - mx) : 0.0f;
        float sum = e;
        #pragma unroll
        for (int off = 32; off; off >>= 1) sum += __shfl_down(sum, off);
        sum = __shfl(sum, 0);
        if (lane < M_SLOTS) wT[lane * B_SZ + b] = e / sum;
    }
}

// ---------------------------------------------------------------------------
// Kernel C: weighted sum. One thread per spatial position, 64 batch
// accumulators in registers so pool is read exactly once.
// grid = 802816/256 = 3136, block = 256.
// ---------------------------------------------------------------------------
__global__ __launch_bounds__(256) void wsum_kernel(const float* __restrict__ pool,
                                                   const float* __restrict__ wT,
                                                   float* __restrict__ out) {
    const int pos = blockIdx.x * 256 + threadIdx.x;  // [0, POS)

    float acc[B_SZ];
    #pragma unroll
    for (int b = 0; b < B_SZ; ++b) acc[b] = 0.0f;

    #pragma unroll 4
    for (int m = 0; m < M_SLOTS; ++m) {
        const float p = pool[(size_t)m * POS + pos];     // coalesced across lanes
        #pragma unroll
        for (int b = 0; b < B_SZ; ++b) {
            acc[b] = fmaf(wT[m * B_SZ + b], p, acc[b]);  // wT index wave-uniform -> s_load
        }
    }

    #pragma unroll
    for (int b = 0; b < B_SZ; ++b) {
        out[(size_t)b * POS + pos] = acc[b];             // coalesced across lanes
    }
}

// ---------------------------------------------------------------------------
extern "C" void kernel_launch(void* const* d_in, const int* in_sizes, int n_in,
                              void* d_out, int out_size, void* d_ws, size_t ws_size,
                              hipStream_t stream) {
    const float* pool = (const float*)d_in[0];   // [60,256,56,56]
    const float* q    = (const float*)d_in[1];   // [64,256]
    float* out        = (float*)d_out;           // [64,256,56,56]

    float* sums = (float*)d_ws;                              // 60*256 floats = 61440 B
    float* wT   = (float*)((char*)d_ws + M_SLOTS * C_CH * sizeof(float));  // 60*64 floats

    avg_kernel<<<(M_SLOTS * C_CH) / 4, 256, 0, stream>>>(pool, sums);
    weights_kernel<<<B_SZ, 256, 0, stream>>>(q, sums, wT);
    wsum_kernel<<<POS / 256, 256, 0, stream>>>(pool, wT, out);
}